// Round 1
// baseline (245.085 us; speedup 1.0000x reference)
//
#include <hip/hip_runtime.h>
#include <math.h>

// Problem constants (from reference setup_inputs)
#define DIMA 1024   // A
#define KK   8      // K
#define PP   4      // P
#define D1   1025   // DIM+1

__device__ __constant__ float kLOG2PI = 1.8378770664093453f;

// Main kernel: one block per 'a' (1024 blocks), 256 threads = 4 waves.
// Each wave handles 8 (p,k) rows. LDS holds c[k][j] = g*(theta - m).
__global__ __launch_bounds__(256, 4) void mp_main(
    const float* __restrict__ theta,
    const float* __restrict__ m_ks,
    const float* __restrict__ grads,
    const int*   __restrict__ perms,
    double*      __restrict__ acc)
{
    __shared__ float c[KK * D1];   // 32.8 KB -> 4 blocks/CU

    const int a = blockIdx.x;

    // Stage c[k*D1 + j] = grads[k][j] * (theta[j] - m_ks[k][j])
    for (int idx = threadIdx.x; idx < KK * D1; idx += 256) {
        const int k = idx / D1;
        const int j = idx - k * D1;
        c[idx] = grads[idx] * (theta[j] - m_ks[idx]);
    }
    __syncthreads();

    const int wave = threadIdx.x >> 6;
    const int lane = threadIdx.x & 63;

    double lp_acc = 0.0;

    // 32 rows per block: row = p*K + k ; wave w takes rows [8w, 8w+8)
    for (int rr = 0; rr < 8; ++rr) {
        const int row = wave * 8 + rr;
        const int p = row >> 3;        // row / K
        const int k = row & 7;         // row % K
        const float* ck = c + k * D1;
        const int* base = perms + (((size_t)a * PP + p) * KK + k) * D1;

        float s = 0.0f;
        int j01 = 0;                   // lanes 0/1 keep perm[0]/perm[1]
        #pragma unroll
        for (int t = 0; t < 17; ++t) {
            const int r = t * 64 + lane;
            if (r < D1) {
                const int j = base[r];
                if (r >= 2) s += ck[j];
                else        j01 = j;
            }
        }
        // 64-lane butterfly reduction (all lanes end with full sum)
        #pragma unroll
        for (int off = 32; off; off >>= 1) s += __shfl_xor(s, off, 64);

        // broadcast perm[0], perm[1] to all lanes (shuffles must be convergent)
        const int j0 = __shfl(j01, 0, 64);
        const int j1 = __shfl(j01, 1, 64);

        if (lane == 0) {
            const float g0 = grads[k * D1 + j0];
            const float g1 = grads[k * D1 + j1];
            const float d0 = theta[j0] - m_ks[k * D1 + j0] + s;
            const float d1 = theta[j1] - m_ks[k * D1 + j1] + s;
            const float lp = -kLOG2PI
                           + 0.5f * (logf(g0) + logf(g1))
                           - 0.5f * (g0 * d0 * d0 + g1 * d1 * d1);
            lp_acc += (double)lp;
        }
    }

    if (lane == 0) atomicAdd(acc, lp_acc);
}

// Finalize: prior term + scaling, single wave.
__global__ void mp_final(
    const float* __restrict__ theta,
    const void*  __restrict__ alpha_p,
    const double* __restrict__ acc,
    float* __restrict__ out)
{
    const int lane = threadIdx.x;  // 64 threads
    float ssq = 0.0f;
    for (int d = lane; d < D1; d += 64) {
        const float v = theta[d];
        ssq += v * v;
    }
    #pragma unroll
    for (int off = 32; off; off >>= 1) ssq += __shfl_xor(ssq, off, 64);

    if (lane == 0) {
        // alpha may arrive as int32(1) or float32(1.0); sniff the bits.
        const unsigned bits = *(const unsigned*)alpha_p;
        const float alpha = ((bits & 0x7f800000u) == 0u)
                          ? (float)(int)bits
                          : __uint_as_float(bits);
        const float lp_prior = -0.5f * ((float)D1 * kLOG2PI
                                        + (float)D1 * logf(alpha)
                                        + ssq / alpha);
        const double loss = (1.0 - 1.0 / (double)KK) * (double)lp_prior;
        const double loss_pred = acc[0] / (double)(PP * 2 * KK);  // M_COND = 2
        out[0] = (float)(-(loss + loss_pred));
    }
}

extern "C" void kernel_launch(void* const* d_in, const int* in_sizes, int n_in,
                              void* d_out, int out_size, void* d_ws, size_t ws_size,
                              hipStream_t stream)
{
    const float* theta = (const float*)d_in[0];
    const float* m_ks  = (const float*)d_in[1];
    const float* grads = (const float*)d_in[2];
    const int*   perms = (const int*)d_in[3];
    const void*  alpha = d_in[4];

    double* acc = (double*)d_ws;
    hipMemsetAsync(acc, 0, sizeof(double), stream);

    mp_main<<<DIMA, 256, 0, stream>>>(theta, m_ks, grads, perms, acc);
    mp_final<<<1, 64, 0, stream>>>(theta, alpha, acc, (float*)d_out);
}

// Round 3
// 203.189 us; speedup vs baseline: 1.2062x; 1.2062x over previous
//
#include <hip/hip_runtime.h>
#include <math.h>

// Problem constants (from reference setup_inputs)
#define DIMA 1024   // A
#define KK   8      // K
#define PP   4      // P
#define D1   1025   // DIM+1

__device__ __constant__ float kLOG2PI = 1.8378770664093453f;

// Main kernel: one block per 'a' (1024 blocks), 256 threads = 4 waves.
// Each wave handles 8 (p,k) rows. LDS holds c[k][j] = g*(theta - m).
// Per-block partial written to part[blockIdx.x] -- NO global atomics
// (R1 post-mortem: 4096 same-address f64 atomics serialized ~80us tail).
__global__ __launch_bounds__(256, 4) void mp_main(
    const float* __restrict__ theta,
    const float* __restrict__ m_ks,
    const float* __restrict__ grads,
    const int*   __restrict__ perms,
    double*      __restrict__ part)
{
    __shared__ float c[KK * D1];   // 32.8 KB -> 4 blocks/CU
    __shared__ double wsum[4];

    const int a = blockIdx.x;

    // Stage c[k*D1 + j] = grads[k][j] * (theta[j] - m_ks[k][j])
    for (int idx = threadIdx.x; idx < KK * D1; idx += 256) {
        const int k = idx / D1;
        const int j = idx - k * D1;
        c[idx] = grads[idx] * (theta[j] - m_ks[idx]);
    }
    __syncthreads();

    const int wave = threadIdx.x >> 6;
    const int lane = threadIdx.x & 63;

    double lp_acc = 0.0;

    // 32 rows per block: row = p*K + k ; wave w takes rows [8w, 8w+8)
    for (int rr = 0; rr < 8; ++rr) {
        const int row = wave * 8 + rr;
        const int p = row >> 3;        // row / K
        const int k = row & 7;         // row % K
        const float* ck = c + k * D1;
        const int* base = perms + (((size_t)a * PP + p) * KK + k) * D1;

        float s = 0.0f;
        int j01 = 0;                   // lanes 0/1 keep perm[0]/perm[1]
        #pragma unroll
        for (int t = 0; t < 17; ++t) {
            const int r = t * 64 + lane;
            if (r < D1) {
                const int j = base[r];
                if (r >= 2) s += ck[j];
                else        j01 = j;
            }
        }
        // 64-lane butterfly reduction (all lanes end with full sum)
        #pragma unroll
        for (int off = 32; off; off >>= 1) s += __shfl_xor(s, off, 64);

        // broadcast perm[0], perm[1] to all lanes (shuffles must be convergent)
        const int j0 = __shfl(j01, 0, 64);
        const int j1 = __shfl(j01, 1, 64);

        if (lane == 0) {
            const float g0 = grads[k * D1 + j0];
            const float g1 = grads[k * D1 + j1];
            const float d0 = theta[j0] - m_ks[k * D1 + j0] + s;
            const float d1 = theta[j1] - m_ks[k * D1 + j1] + s;
            const float lp = -kLOG2PI
                           + 0.5f * (logf(g0) + logf(g1))
                           - 0.5f * (g0 * d0 * d0 + g1 * d1 * d1);
            lp_acc += (double)lp;
        }
    }

    // Block-level reduce: one LDS slot per wave, thread 0 stores the block sum.
    if (lane == 0) wsum[wave] = lp_acc;
    __syncthreads();
    if (threadIdx.x == 0) {
        part[a] = wsum[0] + wsum[1] + wsum[2] + wsum[3];
    }
}

// Finalize: reduce 1024 block partials + prior term. One block of 256.
__global__ void mp_final(
    const float* __restrict__ theta,
    const void*  __restrict__ alpha_p,
    const double* __restrict__ part,
    float* __restrict__ out)
{
    __shared__ double wred[4];
    const int tid = threadIdx.x;
    const int wave = tid >> 6;
    const int lane = tid & 63;

    double psum = 0.0;
    #pragma unroll
    for (int t = 0; t < 4; ++t) psum += part[t * 256 + tid];
    #pragma unroll
    for (int off = 32; off; off >>= 1) psum += __shfl_xor(psum, off, 64);
    if (lane == 0) wred[wave] = psum;

    float ssq = 0.0f;
    for (int d = tid; d < D1; d += 256) {
        const float v = theta[d];
        ssq += v * v;
    }
    __syncthreads();

    // reduce ssq across the block via LDS
    __shared__ float fred[4];
    #pragma unroll
    for (int off = 32; off; off >>= 1) ssq += __shfl_xor(ssq, off, 64);
    if (lane == 0) fred[wave] = ssq;
    __syncthreads();

    if (tid == 0) {
        const double acc = wred[0] + wred[1] + wred[2] + wred[3];
        const float ssq_all = fred[0] + fred[1] + fred[2] + fred[3];
        // alpha may arrive as int32(1) or float32(1.0); sniff the bits.
        const unsigned bits = *(const unsigned*)alpha_p;
        const float alpha = ((bits & 0x7f800000u) == 0u)
                          ? (float)(int)bits
                          : __uint_as_float(bits);
        const float lp_prior = -0.5f * ((float)D1 * kLOG2PI
                                        + (float)D1 * logf(alpha)
                                        + ssq_all / alpha);
        const double loss = (1.0 - 1.0 / (double)KK) * (double)lp_prior;
        const double loss_pred = acc / (double)(PP * 2 * KK);  // M_COND = 2
        out[0] = (float)(-(loss + loss_pred));
    }
}

extern "C" void kernel_launch(void* const* d_in, const int* in_sizes, int n_in,
                              void* d_out, int out_size, void* d_ws, size_t ws_size,
                              hipStream_t stream)
{
    const float* theta = (const float*)d_in[0];
    const float* m_ks  = (const float*)d_in[1];
    const float* grads = (const float*)d_in[2];
    const int*   perms = (const int*)d_in[3];
    const void*  alpha = d_in[4];

    double* part = (double*)d_ws;   // 1024 doubles; every slot written each call

    mp_main<<<DIMA, 256, 0, stream>>>(theta, m_ks, grads, perms, part);
    mp_final<<<1, 256, 0, stream>>>(theta, alpha, part, (float*)d_out);
}

// Round 6
// 181.679 us; speedup vs baseline: 1.3490x; 1.1184x over previous
//
#include <hip/hip_runtime.h>
#include <math.h>

// Problem constants (from reference setup_inputs)
#define DIMA 1024   // A
#define KK   8      // K
#define PP   4      // P
#define D1   1025   // DIM+1
#define NROWS (DIMA * PP * KK)   // 32768

__device__ __constant__ float kLOG2PI = 1.8378770664093453f;

// KEY IDENTITY (R3): perm is a permutation of [0,D1), so
//   S = sum_{r>=2} c_k[perm[r]] = (sum_j c_k[j]) - c_k[perm[0]] - c_k[perm[1]]
// with c_k[j] = g_k[j]*(theta[j]-m_k[j]). Only perm[:, :2] is needed ->
// 256 KB of the 134 MB perms array is touched.

// Prep: C_k = sum_j c_k[j], f64-accumulated. One block, 8 waves (wave = k).
__global__ __launch_bounds__(512) void mp_prep(
    const float* __restrict__ theta,
    const float* __restrict__ m_ks,
    const float* __restrict__ grads,
    double*      __restrict__ Ck)     // ws[0..7]
{
    const int k    = threadIdx.x >> 6;   // 0..7
    const int lane = threadIdx.x & 63;
    const float* gk = grads + k * D1;
    const float* mk = m_ks  + k * D1;

    double s = 0.0;
    for (int j = lane; j < D1; j += 64)
        s += (double)(gk[j] * (theta[j] - mk[j]));

    #pragma unroll
    for (int off = 32; off; off >>= 1) s += __shfl_xor(s, off, 64);
    if (lane == 0) Ck[k] = s;
}

// Rows: one thread per (a,p,k) row. Loads perm[0],perm[1] only.
__global__ __launch_bounds__(128) void mp_rows(
    const float* __restrict__ theta,
    const float* __restrict__ m_ks,
    const float* __restrict__ grads,
    const int*   __restrict__ perms,
    const double* __restrict__ Ck,    // ws[0..7]
    double*      __restrict__ part)   // ws[8..8+gridDim)
{
    __shared__ double wsum[2];
    const int tid = threadIdx.x;
    const int row = blockIdx.x * 128 + tid;     // 0..32767
    const int k   = row & 7;                    // row = a*32 + p*8 + k

    const int* pr = perms + (size_t)row * D1;
    const int j0 = pr[0];
    const int j1 = pr[1];

    const float* gk = grads + k * D1;
    const float* mk = m_ks  + k * D1;

    const float g0 = gk[j0];
    const float g1 = gk[j1];
    const float diff0 = theta[j0] - mk[j0];
    const float diff1 = theta[j1] - mk[j1];

    const float S  = (float)Ck[k] - g0 * diff0 - g1 * diff1;
    const float d0 = diff0 + S;
    const float d1 = diff1 + S;

    const float lp = -kLOG2PI
                   + 0.5f * (logf(g0) + logf(g1))
                   - 0.5f * (g0 * d0 * d0 + g1 * d1 * d1);

    double v = (double)lp;
    #pragma unroll
    for (int off = 32; off; off >>= 1) v += __shfl_xor(v, off, 64);

    const int wave = tid >> 6;
    const int lane = tid & 63;
    if (lane == 0) wsum[wave] = v;
    __syncthreads();
    if (tid == 0) part[blockIdx.x] = wsum[0] + wsum[1];
}

// Finalize: reduce 256 block partials + prior term. One block of 256.
__global__ void mp_final(
    const float* __restrict__ theta,
    const void*  __restrict__ alpha_p,
    const double* __restrict__ part,  // 256 partials
    float* __restrict__ out)
{
    __shared__ double wred[4];
    __shared__ float  fred[4];
    const int tid  = threadIdx.x;
    const int wave = tid >> 6;
    const int lane = tid & 63;

    double psum = part[tid];
    #pragma unroll
    for (int off = 32; off; off >>= 1) psum += __shfl_xor(psum, off, 64);
    if (lane == 0) wred[wave] = psum;

    float ssq = 0.0f;
    for (int d = tid; d < D1; d += 256) {
        const float v = theta[d];
        ssq += v * v;
    }
    #pragma unroll
    for (int off = 32; off; off >>= 1) ssq += __shfl_xor(ssq, off, 64);
    if (lane == 0) fred[wave] = ssq;
    __syncthreads();

    if (tid == 0) {
        const double acc = wred[0] + wred[1] + wred[2] + wred[3];
        const float ssq_all = fred[0] + fred[1] + fred[2] + fred[3];
        // alpha may arrive as int32(1) or float32(1.0); sniff the bits.
        const unsigned bits = *(const unsigned*)alpha_p;
        const float alpha = ((bits & 0x7f800000u) == 0u)
                          ? (float)(int)bits
                          : __uint_as_float(bits);
        const float lp_prior = -0.5f * ((float)D1 * kLOG2PI
                                        + (float)D1 * logf(alpha)
                                        + ssq_all / alpha);
        const double loss = (1.0 - 1.0 / (double)KK) * (double)lp_prior;
        const double loss_pred = acc / (double)(PP * 2 * KK);  // M_COND = 2
        out[0] = (float)(-(loss + loss_pred));
    }
}

extern "C" void kernel_launch(void* const* d_in, const int* in_sizes, int n_in,
                              void* d_out, int out_size, void* d_ws, size_t ws_size,
                              hipStream_t stream)
{
    const float* theta = (const float*)d_in[0];
    const float* m_ks  = (const float*)d_in[1];
    const float* grads = (const float*)d_in[2];
    const int*   perms = (const int*)d_in[3];
    const void*  alpha = d_in[4];

    double* Ck   = (double*)d_ws;        // 8 doubles
    double* part = Ck + 8;               // 256 doubles; all written each call

    mp_prep<<<1, 512, 0, stream>>>(theta, m_ks, grads, Ck);
    mp_rows<<<NROWS / 128, 128, 0, stream>>>(theta, m_ks, grads, perms, Ck, part);
    mp_final<<<1, 256, 0, stream>>>(theta, alpha, part, (float*)d_out);
}